// Round 2
// baseline (417.040 us; speedup 1.0000x reference)
//
#include <hip/hip_runtime.h>
#include <math.h>

#define BATCH   131072
#define IN_DIMS 512
#define TPB     256
#define CHUNK   32
#define NCHUNK  (IN_DIMS / CHUNK)   // 16
#define LSTRIDE 33                  // +1 pad: LDS read bank = (t+k)%32, conflict-free

// Per-block: stage x[256 rows x 32 cols] in LDS (coalesced), each thread owns one
// row and accumulates its 9-dim projection against scalar-loaded W; then each
// thread does a branchless fp32 Jacobi eigensolve of M^T M and emits the
// nearest rotation R = U diag(1,1,det) V^T.
__global__ __launch_bounds__(TPB, 2)
void svdo_rot_kernel(const float* __restrict__ x,
                     const float* __restrict__ W,
                     const float* __restrict__ bias,
                     float* __restrict__ out)
{
    __shared__ float tile[TPB * LSTRIDE];   // 33792 B

    const int t = threadIdx.x;
    const int row0 = blockIdx.x * TPB;
    const float* xb = x + (size_t)row0 * IN_DIMS;

    float acc[9];
#pragma unroll
    for (int j = 0; j < 9; ++j) acc[j] = bias[j];

    // ---- phase 1: tiled GEMV, software-pipelined (prefetch chunk c+1 into regs) ----
    float4 pre[8];
#pragma unroll
    for (int i = 0; i < 8; ++i) {
        int f = i * TPB + t;
        int r = f >> 3, q = f & 7;
        pre[i] = *reinterpret_cast<const float4*>(xb + r * IN_DIMS + q * 4);
    }

#pragma unroll 1
    for (int c = 0; c < NCHUNK; ++c) {
        __syncthreads();
#pragma unroll
        for (int i = 0; i < 8; ++i) {
            int f = i * TPB + t;
            int r = f >> 3, q = f & 7;
            float* p = &tile[r * LSTRIDE + q * 4];
            p[0] = pre[i].x; p[1] = pre[i].y; p[2] = pre[i].z; p[3] = pre[i].w;
        }
        __syncthreads();
        if (c + 1 < NCHUNK) {
#pragma unroll
            for (int i = 0; i < 8; ++i) {
                int f = i * TPB + t;
                int r = f >> 3, q = f & 7;
                pre[i] = *reinterpret_cast<const float4*>(
                    xb + r * IN_DIMS + (c + 1) * CHUNK + q * 4);
            }
        }
        float xv[CHUNK];
#pragma unroll
        for (int k = 0; k < CHUNK; ++k) xv[k] = tile[t * LSTRIDE + k];
        const float* wc = W + c * CHUNK;
#pragma unroll
        for (int j = 0; j < 9; ++j) {
            float s = acc[j];
            const float* wr = wc + j * IN_DIMS;   // uniform address -> s_load
#pragma unroll
            for (int k = 0; k < CHUNK; ++k) s = fmaf(xv[k], wr[k], s);
            acc[j] = s;
        }
    }

    // ---- phase 2: nearest rotation of the 3x3 M (row-major acc[3r+c]), fp32 ----
    float m0 = acc[0], m1 = acc[1], m2 = acc[2];
    float m3 = acc[3], m4 = acc[4], m5 = acc[5];
    float m6 = acc[6], m7 = acc[7], m8 = acc[8];

    // A = M^T M (symmetric)
    float A00 = m0*m0 + m3*m3 + m6*m6;
    float A01 = m0*m1 + m3*m4 + m6*m7;
    float A02 = m0*m2 + m3*m5 + m6*m8;
    float A11 = m1*m1 + m4*m4 + m7*m7;
    float A12 = m1*m2 + m4*m5 + m7*m8;
    float A22 = m2*m2 + m5*m5 + m8*m8;

    // V = I (columns V0,V1,V2 are eigenvectors)
    float V0x = 1.f, V0y = 0.f, V0z = 0.f;
    float V1x = 0.f, V1y = 1.f, V1z = 0.f;
    float V2x = 0.f, V2y = 0.f, V2z = 1.f;

    // Branchless Jacobi rotation zeroing Apq:
    //   d = Aqq - App;  tt = 2*Apq / (d + copysign(sqrt(d^2 + 4*Apq^2), d))
    //   App -= tt*Apq;  Aqq += tt*Apq
    // Guard: |denom| >= sqrt(...) >= 2|Apq|; denom==0 only when Apq==0 too
    // (then numerator==0 and the +-1e-30 keeps it 0/finite = 0).
#define JACOBI_ROT(App, Aqq, Apq, Arp, Arq, Px, Py, Pz, Qx, Qy, Qz)            \
    do {                                                                       \
        float dpr = Aqq - App;                                                 \
        float sq  = sqrtf(fmaf(dpr, dpr, 4.0f * Apq * Apq));                   \
        float dd  = dpr + copysignf(sq, dpr);                                  \
        float tt  = (2.0f * Apq) / (dd + copysignf(1e-30f, dd));               \
        float cc  = 1.0f / sqrtf(fmaf(tt, tt, 1.0f));                          \
        float ss  = tt * cc;                                                   \
        App -= tt * Apq; Aqq += tt * Apq;                                      \
        float nrp = cc*Arp - ss*Arq;  Arq = ss*Arp + cc*Arq;  Arp = nrp;       \
        Apq = 0.0f;                                                            \
        float tx = cc*Px - ss*Qx;  Qx = ss*Px + cc*Qx;  Px = tx;               \
        float ty = cc*Py - ss*Qy;  Qy = ss*Py + cc*Qy;  Py = ty;               \
        float tz = cc*Pz - ss*Qz;  Qz = ss*Pz + cc*Qz;  Pz = tz;               \
    } while (0)

#pragma unroll 1
    for (int sweep = 0; sweep < 5; ++sweep) {
        JACOBI_ROT(A00, A11, A01, A02, A12, V0x,V0y,V0z, V1x,V1y,V1z);
        JACOBI_ROT(A00, A22, A02, A01, A12, V0x,V0y,V0z, V2x,V2y,V2z);
        JACOBI_ROT(A11, A22, A12, A01, A02, V1x,V1y,V1z, V2x,V2y,V2z);
    }

    // sort eigenpairs descending (column swaps, no dynamic indexing)
#define CSWAP(La, Lb, Ax, Ay, Az, Bx, By, Bz)                                  \
    do { if (La < Lb) { float _t_;                                             \
        _t_ = La; La = Lb; Lb = _t_;                                           \
        _t_ = Ax; Ax = Bx; Bx = _t_;                                           \
        _t_ = Ay; Ay = By; By = _t_;                                           \
        _t_ = Az; Az = Bz; Bz = _t_;                                           \
    } } while (0)

    CSWAP(A00, A11, V0x,V0y,V0z, V1x,V1y,V1z);
    CSWAP(A00, A22, V0x,V0y,V0z, V2x,V2y,V2z);
    CSWAP(A11, A22, V1x,V1y,V1z, V2x,V2y,V2z);

    // u1 = normalize(M v1)
    float b1x = m0*V0x + m1*V0y + m2*V0z;
    float b1y = m3*V0x + m4*V0y + m5*V0z;
    float b1z = m6*V0x + m7*V0y + m8*V0z;
    float inv1 = 1.0f / sqrtf(b1x*b1x + b1y*b1y + b1z*b1z + 1e-30f);
    float u1x = b1x*inv1, u1y = b1y*inv1, u1z = b1z*inv1;

    // u2 = normalize(M v2 - (u1 . M v2) u1)
    float b2x = m0*V1x + m1*V1y + m2*V1z;
    float b2y = m3*V1x + m4*V1y + m5*V1z;
    float b2z = m6*V1x + m7*V1y + m8*V1z;
    float d12 = u1x*b2x + u1y*b2y + u1z*b2z;
    b2x -= d12*u1x; b2y -= d12*u1y; b2z -= d12*u1z;
    float inv2 = 1.0f / sqrtf(b2x*b2x + b2y*b2y + b2z*b2z + 1e-30f);
    float u2x = b2x*inv2, u2y = b2y*inv2, u2z = b2z*inv2;

    // u3 = u1 x u2  (det(U) = +1 by construction)
    float u3x = u1y*u2z - u1z*u2y;
    float u3y = u1z*u2x - u1x*u2z;
    float u3z = u1x*u2y - u1y*u2x;

    // e = sign(det V); R = u1 v1^T + u2 v2^T + e u3 v3^T
    float cxx = V1y*V2z - V1z*V2y;
    float cyy = V1z*V2x - V1x*V2z;
    float czz = V1x*V2y - V1y*V2x;
    float detV = V0x*cxx + V0y*cyy + V0z*czz;
    float e = (detV >= 0.0f) ? 1.0f : -1.0f;
    float w3x = e*u3x, w3y = e*u3y, w3z = e*u3z;

    float* o = out + (size_t)(row0 + t) * 9;
    o[0] = u1x*V0x + u2x*V1x + w3x*V2x;
    o[1] = u1x*V0y + u2x*V1y + w3x*V2y;
    o[2] = u1x*V0z + u2x*V1z + w3x*V2z;
    o[3] = u1y*V0x + u2y*V1x + w3y*V2x;
    o[4] = u1y*V0y + u2y*V1y + w3y*V2y;
    o[5] = u1y*V0z + u2y*V1z + w3y*V2z;
    o[6] = u1z*V0x + u2z*V1x + w3z*V2x;
    o[7] = u1z*V0y + u2z*V1y + w3z*V2y;
    o[8] = u1z*V0z + u2z*V1z + w3z*V2z;
}

extern "C" void kernel_launch(void* const* d_in, const int* in_sizes, int n_in,
                              void* d_out, int out_size, void* d_ws, size_t ws_size,
                              hipStream_t stream) {
    const float* x  = (const float*)d_in[0];
    const float* W  = (const float*)d_in[1];
    const float* b  = (const float*)d_in[2];
    float* out = (float*)d_out;
    svdo_rot_kernel<<<dim3(BATCH / TPB), dim3(TPB), 0, stream>>>(x, W, b, out);
}

// Round 3
// 365.668 us; speedup vs baseline: 1.1405x; 1.1405x over previous
//
#include <hip/hip_runtime.h>
#include <math.h>

#define BATCH    131072
#define IN_DIMS  512
#define TPB      256
#define ROWS     64                 // rows per block
#define NBLK     (BATCH / ROWS)     // 2048 blocks = 8 blocks/CU
#define CHUNK    32
#define NCHUNK   (IN_DIMS / CHUNK)  // 16
#define LSTRIDE  33                 // +1 pad: read bank = (l + 8w + k) % 32, conflict-free
#define KSLICE   8                  // cols per wave per chunk (split-K across 4 waves)

// 64 rows/block, 4 waves split the K dimension (wave w owns cols c*32+w*8..+8 of
// each chunk). Ping-pong LDS tile (one barrier/chunk), depth-2 register prefetch,
// W slices scalarized to s_loads (72 floats/chunk/wave fits SGPRs). Cross-wave
// reduce via LDS; wave 0 runs the fp32 Jacobi nearest-rotation epilogue.
__global__ __launch_bounds__(TPB, 4)
void svdo_rot_kernel(const float* __restrict__ x,
                     const float* __restrict__ W,
                     const float* __restrict__ bias,
                     float* __restrict__ out)
{
    __shared__ float tile[2][ROWS * LSTRIDE];   // 2 x 8448 B = 16896 B

    const int t = threadIdx.x;
    const int l = t & 63;
    const int w = __builtin_amdgcn_readfirstlane(t >> 6);   // wave id 0..3, uniform
    const int row0 = blockIdx.x * ROWS;
    const float* xb = x + (size_t)row0 * IN_DIMS;

    float acc[9];
#pragma unroll
    for (int j = 0; j < 9; ++j) acc[j] = 0.0f;

    float4 pre[2];

#define LOADCH(c)                                                              \
    do { _Pragma("unroll")                                                     \
        for (int i = 0; i < 2; ++i) {                                          \
            int f = i * TPB + t;                                               \
            int r = f >> 3, q = f & 7;                                         \
            pre[i] = *reinterpret_cast<const float4*>(                         \
                xb + r * IN_DIMS + (c) * CHUNK + q * 4);                       \
        } } while (0)

#define WRITECH(buf)                                                           \
    do { _Pragma("unroll")                                                     \
        for (int i = 0; i < 2; ++i) {                                          \
            int f = i * TPB + t;                                               \
            int r = f >> 3, q = f & 7;                                         \
            float* p = &tile[buf][r * LSTRIDE + q * 4];                        \
            p[0] = pre[i].x; p[1] = pre[i].y; p[2] = pre[i].z; p[3] = pre[i].w;\
        } } while (0)

    // prologue: chunk 0 -> buf0; chunk 1 in regs
    LOADCH(0);
    WRITECH(0);
    LOADCH(1);
    __syncthreads();

#pragma unroll 2
    for (int c = 0; c < NCHUNK; ++c) {
        const int buf = c & 1;
        if (c + 1 < NCHUNK) WRITECH(1 - buf);   // stage chunk c+1 (regs -> other buf)
        if (c + 2 < NCHUNK) LOADCH(c + 2);      // prefetch chunk c+2 into regs

        float xv[KSLICE];
#pragma unroll
        for (int k = 0; k < KSLICE; ++k)
            xv[k] = tile[buf][l * LSTRIDE + w * KSLICE + k];

        const float* wc = W + c * CHUNK + w * KSLICE;   // uniform -> s_load
#pragma unroll
        for (int j = 0; j < 9; ++j) {
            float s = acc[j];
            const float* wr = wc + j * IN_DIMS;
#pragma unroll
            for (int k = 0; k < KSLICE; ++k) s = fmaf(xv[k], wr[k], s);
            acc[j] = s;
        }
        __syncthreads();
    }

    // ---- cross-wave reduction: waves 1..3 dump partials, wave 0 sums ----
    float* red = &tile[0][0];   // 3*64*9 = 1728 floats <= 4224 available
    if (w > 0) {
#pragma unroll
        for (int j = 0; j < 9; ++j) red[(w - 1) * (ROWS * 9) + l * 9 + j] = acc[j];
    }
    __syncthreads();
    if (w != 0) return;

    float m[9];
#pragma unroll
    for (int j = 0; j < 9; ++j)
        m[j] = bias[j] + acc[j]
             + red[0 * (ROWS * 9) + l * 9 + j]
             + red[1 * (ROWS * 9) + l * 9 + j]
             + red[2 * (ROWS * 9) + l * 9 + j];

    // ---- nearest rotation of the 3x3 M (row-major m[3r+c]), fp32 Jacobi ----
    float m0 = m[0], m1 = m[1], m2 = m[2];
    float m3 = m[3], m4 = m[4], m5 = m[5];
    float m6 = m[6], m7 = m[7], m8 = m[8];

    float A00 = m0*m0 + m3*m3 + m6*m6;
    float A01 = m0*m1 + m3*m4 + m6*m7;
    float A02 = m0*m2 + m3*m5 + m6*m8;
    float A11 = m1*m1 + m4*m4 + m7*m7;
    float A12 = m1*m2 + m4*m5 + m7*m8;
    float A22 = m2*m2 + m5*m5 + m8*m8;

    float V0x = 1.f, V0y = 0.f, V0z = 0.f;
    float V1x = 0.f, V1y = 1.f, V1z = 0.f;
    float V2x = 0.f, V2y = 0.f, V2z = 1.f;

#define JACOBI_ROT(App, Aqq, Apq, Arp, Arq, Px, Py, Pz, Qx, Qy, Qz)            \
    do {                                                                       \
        float dpr = Aqq - App;                                                 \
        float sq  = sqrtf(fmaf(dpr, dpr, 4.0f * Apq * Apq));                   \
        float dd  = dpr + copysignf(sq, dpr);                                  \
        float tt  = (2.0f * Apq) / (dd + copysignf(1e-30f, dd));               \
        float cc  = 1.0f / sqrtf(fmaf(tt, tt, 1.0f));                          \
        float ss  = tt * cc;                                                   \
        App -= tt * Apq; Aqq += tt * Apq;                                      \
        float nrp = cc*Arp - ss*Arq;  Arq = ss*Arp + cc*Arq;  Arp = nrp;       \
        Apq = 0.0f;                                                            \
        float tx = cc*Px - ss*Qx;  Qx = ss*Px + cc*Qx;  Px = tx;               \
        float ty = cc*Py - ss*Qy;  Qy = ss*Py + cc*Qy;  Py = ty;               \
        float tz = cc*Pz - ss*Qz;  Qz = ss*Pz + cc*Qz;  Pz = tz;               \
    } while (0)

#pragma unroll 1
    for (int sweep = 0; sweep < 5; ++sweep) {
        JACOBI_ROT(A00, A11, A01, A02, A12, V0x,V0y,V0z, V1x,V1y,V1z);
        JACOBI_ROT(A00, A22, A02, A01, A12, V0x,V0y,V0z, V2x,V2y,V2z);
        JACOBI_ROT(A11, A22, A12, A01, A02, V1x,V1y,V1z, V2x,V2y,V2z);
    }

#define CSWAP(La, Lb, Ax, Ay, Az, Bx, By, Bz)                                  \
    do { if (La < Lb) { float _t_;                                             \
        _t_ = La; La = Lb; Lb = _t_;                                           \
        _t_ = Ax; Ax = Bx; Bx = _t_;                                           \
        _t_ = Ay; Ay = By; By = _t_;                                           \
        _t_ = Az; Az = Bz; Bz = _t_;                                           \
    } } while (0)

    CSWAP(A00, A11, V0x,V0y,V0z, V1x,V1y,V1z);
    CSWAP(A00, A22, V0x,V0y,V0z, V2x,V2y,V2z);
    CSWAP(A11, A22, V1x,V1y,V1z, V2x,V2y,V2z);

    // u1 = normalize(M v1)
    float b1x = m0*V0x + m1*V0y + m2*V0z;
    float b1y = m3*V0x + m4*V0y + m5*V0z;
    float b1z = m6*V0x + m7*V0y + m8*V0z;
    float inv1 = 1.0f / sqrtf(b1x*b1x + b1y*b1y + b1z*b1z + 1e-30f);
    float u1x = b1x*inv1, u1y = b1y*inv1, u1z = b1z*inv1;

    // u2 = normalize(M v2 - (u1 . M v2) u1)
    float b2x = m0*V1x + m1*V1y + m2*V1z;
    float b2y = m3*V1x + m4*V1y + m5*V1z;
    float b2z = m6*V1x + m7*V1y + m8*V1z;
    float d12 = u1x*b2x + u1y*b2y + u1z*b2z;
    b2x -= d12*u1x; b2y -= d12*u1y; b2z -= d12*u1z;
    float inv2 = 1.0f / sqrtf(b2x*b2x + b2y*b2y + b2z*b2z + 1e-30f);
    float u2x = b2x*inv2, u2y = b2y*inv2, u2z = b2z*inv2;

    // u3 = u1 x u2  (det(U) = +1 by construction)
    float u3x = u1y*u2z - u1z*u2y;
    float u3y = u1z*u2x - u1x*u2z;
    float u3z = u1x*u2y - u1y*u2x;

    // e = sign(det V); R = u1 v1^T + u2 v2^T + e u3 v3^T
    float cxx = V1y*V2z - V1z*V2y;
    float cyy = V1z*V2x - V1x*V2z;
    float czz = V1x*V2y - V1y*V2x;
    float detV = V0x*cxx + V0y*cyy + V0z*czz;
    float e = (detV >= 0.0f) ? 1.0f : -1.0f;
    float w3x = e*u3x, w3y = e*u3y, w3z = e*u3z;

    float* o = out + (size_t)(row0 + l) * 9;
    o[0] = u1x*V0x + u2x*V1x + w3x*V2x;
    o[1] = u1x*V0y + u2x*V1y + w3x*V2y;
    o[2] = u1x*V0z + u2x*V1z + w3x*V2z;
    o[3] = u1y*V0x + u2y*V1x + w3y*V2x;
    o[4] = u1y*V0y + u2y*V1y + w3y*V2y;
    o[5] = u1y*V0z + u2y*V1z + w3y*V2z;
    o[6] = u1z*V0x + u2z*V1x + w3z*V2x;
    o[7] = u1z*V0y + u2z*V1y + w3z*V2y;
    o[8] = u1z*V0z + u2z*V1z + w3z*V2z;
}

extern "C" void kernel_launch(void* const* d_in, const int* in_sizes, int n_in,
                              void* d_out, int out_size, void* d_ws, size_t ws_size,
                              hipStream_t stream) {
    const float* x  = (const float*)d_in[0];
    const float* W  = (const float*)d_in[1];
    const float* b  = (const float*)d_in[2];
    float* out = (float*)d_out;
    svdo_rot_kernel<<<dim3(NBLK), dim3(TPB), 0, stream>>>(x, W, b, out);
}